// Round 2
// baseline (868.944 us; speedup 1.0000x reference)
//
#include <hip/hip_runtime.h>
#include <hip/hip_bf16.h>
#include <stdint.h>

// Swin windowed MHA: N=32, H=W=64, C=512, heads=16, head_dim=32, window 8x8 (E=64).
// conv x->bf16 ; transpose weights ; GEMM1(qkv, 256^2 8-phase)+scatter ; windowed attn ;
// GEMM2(out, 256^2 8-phase).

typedef __attribute__((ext_vector_type(4))) float  f32x4;
typedef __attribute__((ext_vector_type(4))) float  fvec4;
typedef __attribute__((ext_vector_type(8))) short  s16x8;
typedef __attribute__((ext_vector_type(8))) __bf16 bf16x8;
typedef unsigned short u16;
typedef unsigned int   u32;
typedef __attribute__((ext_vector_type(4))) u16 u16x4;

__device__ __forceinline__ u16 f2bf(float f) {
  u32 u = __builtin_bit_cast(u32, f);
  u32 r = (u + 0x7FFFu + ((u >> 16) & 1u)) >> 16;
  return (u16)r;
}

__device__ __forceinline__ f32x4 mfma16(s16x8 a, s16x8 b, f32x4 c) {
  return __builtin_amdgcn_mfma_f32_16x16x32_bf16((bf16x8)a, (bf16x8)b, c, 0, 0, 0);
}

__device__ __forceinline__ void gload16(const u16* g, u16* l) {
  __builtin_amdgcn_global_load_lds(
      (const __attribute__((address_space(1))) u32*)g,
      (__attribute__((address_space(3))) u32*)l, 16, 0, 0);
}

// ---------------- conversion kernels ----------------
__global__ void k_conv_x(const float* __restrict__ x, u16* __restrict__ xb, int n4) {
  int i = blockIdx.x * 256 + threadIdx.x;
  if (i >= n4) return;
  fvec4 v = ((const fvec4*)x)[i];
  u16x4 o;
  o.x = f2bf(v.x); o.y = f2bf(v.y); o.z = f2bf(v.z); o.w = f2bf(v.w);
  ((u16x4*)xb)[i] = o;
}

__global__ void k_transpose_w(const float* __restrict__ w, u16* __restrict__ wt, int K, int N) {
  int i = blockIdx.x * 256 + threadIdx.x;
  if (i >= K * N) return;
  int k = i / N, n = i - k * N;
  wt[n * K + k] = f2bf(w[i]);
}

// ---------------- GEMM: 256x256 tile, BK=64, 8 waves, 8-phase, K=512 fixed ----------------
// A [M][512] bf16 row-major, B [N][512] bf16 row-major (i.e. weight^T).
// MODE 0: qkv projection -> scatter Q/K/VT (bf16) with qkv_b.
// MODE 1: out projection -> fp32 Out with out_b.
// LDS: 2 dbuf x (256x64) for A and B = 128 KiB. Swizzle: 16B-chunk index ^= (row&7),
// applied on the pre-swizzled GLOBAL source (gload_lds dest stays linear) and on ds_read.
template <int MODE>
__global__ __launch_bounds__(512, 2)
void k_gemm(const u16* __restrict__ A, const u16* __restrict__ B,
            const float* __restrict__ bias,
            u16* __restrict__ Qb, u16* __restrict__ Kb, u16* __restrict__ VT,
            float* __restrict__ Out, int ntn) {
  __shared__ u16 ldsA[2][16384];
  __shared__ u16 ldsB[2][16384];
  const int tid = threadIdx.x;
  const int lane = tid & 63, wid = tid >> 6;
  const int quad = lane >> 4, col_l = lane & 15;
  const int wr = wid >> 2, wc = wid & 3;  // 2 x 4 wave grid; wave tile 128 x 64

  // XCD-chunked bijective swizzle (gridDim.x % 8 == 0)
  const int cpx = gridDim.x >> 3;
  const int sb = (blockIdx.x & 7) * cpx + (blockIdx.x >> 3);
  const int mt = sb / ntn, nt = sb - mt * ntn;
  const int m0 = mt * 256, n0 = nt * 256;

  // staging: thread t covers linear LDS bytes [t*16) per gload g; row=g*64+t/8, chunk=t%8.
  // global source pre-swizzled: fetch chunk (t%8)^(row&7).
  const int srow = tid >> 3;
  const int sch = (tid & 7) ^ (srow & 7);
  const size_t gA = (size_t)(m0 + srow) * 512 + sch * 8;
  const size_t gB = (size_t)(n0 + srow) * 512 + sch * 8;

  auto STAGE = [&](int s) {
    const int b = s & 1;
    const size_t k = (size_t)s * 64;
#pragma unroll
    for (int g = 0; g < 4; ++g) {
      gload16(A + gA + (size_t)g * 32768 + k, &ldsA[b][g * 4096 + tid * 8]);
      gload16(B + gB + (size_t)g * 32768 + k, &ldsB[b][g * 4096 + tid * 8]);
    }
  };

  STAGE(0);
  STAGE(1);
  asm volatile("s_waitcnt vmcnt(8)" ::: "memory");
  asm volatile("s_barrier" ::: "memory");

  const int xsw = (col_l & 7) << 3;               // row&7 == col_l&7 for all frag rows
  const int aRB = (wr * 128 + col_l) * 64;
  const int bRB = (wc * 64 + col_l) * 64;

  f32x4 acc[8][4] = {};

  for (int t = 0; t < 8; ++t) {
    const int bu = t & 1;
    s16x8 af[4][2], bf[4][2];

    // ---- ph0: read af(r0-3,kk0/1)+bf(c,kk0); MFMA r0-3 x c x kk0
#pragma unroll
    for (int r = 0; r < 4; ++r)
#pragma unroll
      for (int kk = 0; kk < 2; ++kk)
        af[r][kk] = *(const s16x8*)&ldsA[bu][aRB + r * 1024 + ((kk * 32 + quad * 8) ^ xsw)];
#pragma unroll
    for (int c = 0; c < 4; ++c)
      bf[c][0] = *(const s16x8*)&ldsB[bu][bRB + c * 1024 + ((quad * 8) ^ xsw)];
    asm volatile("s_barrier" ::: "memory");
    __builtin_amdgcn_s_setprio(1);
#pragma unroll
    for (int r = 0; r < 4; ++r)
#pragma unroll
      for (int c = 0; c < 4; ++c)
        acc[r][c] = mfma16(af[r][0], bf[c][0], acc[r][c]);
    __builtin_amdgcn_s_setprio(0);
    asm volatile("s_barrier" ::: "memory");

    // ---- ph1: read bf(c,kk1); MFMA r0-3 x c x kk1
#pragma unroll
    for (int c = 0; c < 4; ++c)
      bf[c][1] = *(const s16x8*)&ldsB[bu][bRB + c * 1024 + ((32 + quad * 8) ^ xsw)];
    asm volatile("s_barrier" ::: "memory");
    __builtin_amdgcn_s_setprio(1);
#pragma unroll
    for (int r = 0; r < 4; ++r)
#pragma unroll
      for (int c = 0; c < 4; ++c)
        acc[r][c] = mfma16(af[r][1], bf[c][1], acc[r][c]);
    __builtin_amdgcn_s_setprio(0);
    asm volatile("s_barrier" ::: "memory");

    // ---- ph2: read af(r4-7,kk0/1); MFMA r4-7 x c x kk0
#pragma unroll
    for (int r = 0; r < 4; ++r)
#pragma unroll
      for (int kk = 0; kk < 2; ++kk)
        af[r][kk] = *(const s16x8*)&ldsA[bu][aRB + (r + 4) * 1024 + ((kk * 32 + quad * 8) ^ xsw)];
    asm volatile("s_barrier" ::: "memory");
    __builtin_amdgcn_s_setprio(1);
#pragma unroll
    for (int r = 0; r < 4; ++r)
#pragma unroll
      for (int c = 0; c < 4; ++c)
        acc[r + 4][c] = mfma16(af[r][0], bf[c][0], acc[r + 4][c]);
    __builtin_amdgcn_s_setprio(0);
    asm volatile("s_barrier" ::: "memory");
    // all reads of buf[bu] are now complete across all waves -> safe to restage it

    // ---- ph3: stage t+2 into buf[bu]; MFMA r4-7 x c x kk1; counted vmcnt
    if (t < 6) STAGE(t + 2);
    asm volatile("s_barrier" ::: "memory");
    __builtin_amdgcn_s_setprio(1);
#pragma unroll
    for (int r = 0; r < 4; ++r)
#pragma unroll
      for (int c = 0; c < 4; ++c)
        acc[r + 4][c] = mfma16(af[r][1], bf[c][1], acc[r + 4][c]);
    __builtin_amdgcn_s_setprio(0);
    if (t < 6)
      asm volatile("s_waitcnt vmcnt(8)" ::: "memory");   // tile t+1 fully landed
    else if (t == 6)
      asm volatile("s_waitcnt vmcnt(0)" ::: "memory");   // drain tail
    asm volatile("s_barrier" ::: "memory");
  }

  // ---- epilogue
#pragma unroll
  for (int r = 0; r < 8; ++r) {
#pragma unroll
    for (int c = 0; c < 4; ++c) {
      const int cc = n0 + wc * 64 + c * 16 + col_l;
      const float bv = bias[cc];
      f32x4 v = acc[r][c];
      if (MODE == 0) {
        const int which = cc >> 9, rem = cc & 511, head = rem >> 5, d = rem & 31;
#pragma unroll
        for (int i = 0; i < 4; ++i) {
          const int m = m0 + wr * 128 + r * 16 + quad * 4 + i;
          const int nimg = m >> 12, h = (m >> 6) & 63, w = m & 63;
          const int win = nimg * 64 + (h >> 3) * 8 + (w >> 3);
          const int e = (h & 7) * 8 + (w & 7);
          const int base = win * 16 + head;
          const u16 ov = f2bf(v[i] + bv);
          if (which == 0)      Qb[(base * 64 + e) * 32 + d] = ov;
          else if (which == 1) Kb[(base * 64 + e) * 32 + d] = ov;
          else                 VT[(base * 32 + d) * 64 + e] = ov;
        }
      } else {
#pragma unroll
        for (int i = 0; i < 4; ++i) {
          const int m = m0 + wr * 128 + r * 16 + quad * 4 + i;
          Out[(size_t)m * 512 + cc] = v[i] + bv;
        }
      }
    }
  }
}

// ---------------- windowed attention (unchanged) ----------------
__global__ __launch_bounds__(256, 2)
void k_attn(const u16* __restrict__ Q, const u16* __restrict__ K,
            const u16* __restrict__ VT, const float* __restrict__ mask,
            const float* __restrict__ btab, u16* __restrict__ AO) {
  __shared__ u16 plds[4 * 4096];
  const int tid = threadIdx.x;
  const int wid = tid >> 6, lane = tid & 63;
  const int quad = lane >> 4, col_l = lane & 15;
  const int bid = blockIdx.x;
  const int win = bid >> 2;
  const int head = ((bid & 3) << 2) | wid;
  const int nimg = win >> 6, a = (win >> 3) & 7, b = win & 7;
  const size_t wh = (size_t)(win * 16 + head);
  const u16* qb  = Q  + wh * 2048;
  const u16* kb  = K  + wh * 2048;
  const u16* vtb = VT + wh * 2048;

  s16x8 aq[4], bk[4];
#pragma unroll
  for (int t = 0; t < 4; ++t) {
    aq[t] = *(const s16x8*)&qb[(t * 16 + col_l) * 32 + quad * 8];
    bk[t] = *(const s16x8*)&kb[(t * 16 + col_l) * 32 + quad * 8];
  }
  f32x4 s[4][4] = {};
#pragma unroll
  for (int r = 0; r < 4; ++r)
#pragma unroll
    for (int c = 0; c < 4; ++c)
      s[r][c] = mfma16(aq[r], bk[c], s[r][c]);

  const float scale = 0.17677669529663687f;  // 1/sqrt(32)
  const float* mrow = mask + (size_t)(a * 8 + b) * 4096;
#pragma unroll
  for (int r = 0; r < 4; ++r)
#pragma unroll
    for (int c = 0; c < 4; ++c)
#pragma unroll
      for (int i = 0; i < 4; ++i) {
        const int row = r * 16 + quad * 4 + i, col = c * 16 + col_l;
        const int dh = (row >> 3) - (col >> 3) + 7;
        const int dw = (row & 7) - (col & 7) + 7;
        s[r][c][i] = s[r][c][i] * scale + btab[(dh * 15 + dw) * 16 + head] +
                     mrow[row * 64 + col];
      }

  float rinv[4][4];
#pragma unroll
  for (int r = 0; r < 4; ++r) {
#pragma unroll
    for (int i = 0; i < 4; ++i) {
      float mx = fmaxf(fmaxf(s[r][0][i], s[r][1][i]), fmaxf(s[r][2][i], s[r][3][i]));
      mx = fmaxf(mx, __shfl_xor(mx, 1));
      mx = fmaxf(mx, __shfl_xor(mx, 2));
      mx = fmaxf(mx, __shfl_xor(mx, 4));
      mx = fmaxf(mx, __shfl_xor(mx, 8));
      float sum = 0.f;
#pragma unroll
      for (int c = 0; c < 4; ++c) {
        float p = __expf(s[r][c][i] - mx);
        s[r][c][i] = p;
        sum += p;
      }
      sum += __shfl_xor(sum, 1);
      sum += __shfl_xor(sum, 2);
      sum += __shfl_xor(sum, 4);
      sum += __shfl_xor(sum, 8);
      rinv[r][i] = 1.0f / sum;
    }
  }

  u16* pl = &plds[wid * 4096];
#pragma unroll
  for (int r = 0; r < 4; ++r)
#pragma unroll
    for (int c = 0; c < 4; ++c)
#pragma unroll
      for (int i = 0; i < 4; ++i) {
        const int row = r * 16 + quad * 4 + i, col = c * 16 + col_l;
        const int off = (row * 128 + col * 2) ^ ((row & 7) << 4);
        *(u16*)((char*)pl + off) = f2bf(s[r][c][i]);
      }
  __syncthreads();

  s16x8 bv[2][2];
#pragma unroll
  for (int c2 = 0; c2 < 2; ++c2)
#pragma unroll
    for (int ks = 0; ks < 2; ++ks)
      bv[c2][ks] = *(const s16x8*)&vtb[(c2 * 16 + col_l) * 64 + ks * 32 + quad * 8];

  f32x4 o[4][2] = {};
#pragma unroll
  for (int r = 0; r < 4; ++r) {
#pragma unroll
    for (int ks = 0; ks < 2; ++ks) {
      const int row = r * 16 + col_l;
      const int off = (row * 128 + (ks * 32 + quad * 8) * 2) ^ ((row & 7) << 4);
      s16x8 pa = *(const s16x8*)((char*)pl + off);
#pragma unroll
      for (int c2 = 0; c2 < 2; ++c2)
        o[r][c2] = mfma16(pa, bv[c2][ks], o[r][c2]);
    }
  }

#pragma unroll
  for (int r = 0; r < 4; ++r) {
#pragma unroll
    for (int i = 0; i < 4; ++i) {
      const int row = r * 16 + quad * 4 + i;
      const int h = a * 8 + (row >> 3), w = b * 8 + (row & 7);
      const size_t m = (size_t)nimg * 4096 + (size_t)h * 64 + w;
      const float inv = rinv[r][i];
#pragma unroll
      for (int c2 = 0; c2 < 2; ++c2)
        AO[m * 512 + head * 32 + c2 * 16 + col_l] = f2bf(o[r][c2][i] * inv);
    }
  }
}

// ---------------- launch ----------------
extern "C" void kernel_launch(void* const* d_in, const int* in_sizes, int n_in,
                              void* d_out, int out_size, void* d_ws, size_t ws_size,
                              hipStream_t stream) {
  const float* x     = (const float*)d_in[0];
  const float* mask  = (const float*)d_in[1];
  const float* qkv_w = (const float*)d_in[2];
  const float* qkv_b = (const float*)d_in[3];
  const float* out_w = (const float*)d_in[4];
  const float* out_b = (const float*)d_in[5];
  const float* btab  = (const float*)d_in[6];

  char* ws = (char*)d_ws;
  u16* xb    = (u16*)ws;                        // 134,217,728 B (x bf16, reused as attn_out)
  u16* vt    = (u16*)(ws + 134217728);          // 134,217,728 B (V^T)
  u16* wqkvT = (u16*)(ws + 268435456);          // 1,572,864 B
  u16* woT   = (u16*)(ws + 270008320);          // 524,288 B

  u16* Qb = (u16*)d_out;                        // 134,217,728 B
  u16* Kb = (u16*)d_out + 67108864;             // 134,217,728 B

  k_conv_x<<<65536, 256, 0, stream>>>(x, xb, 16777216);
  k_transpose_w<<<3072, 256, 0, stream>>>(qkv_w, wqkvT, 512, 1536);
  k_transpose_w<<<1024, 256, 0, stream>>>(out_w, woT, 512, 512);
  k_gemm<0><<<3072, 512, 0, stream>>>(xb, wqkvT, qkv_b, Qb, Kb, vt, nullptr, 6);
  k_attn<<<8192, 256, 0, stream>>>(Qb, Kb, vt, mask, btab, xb);
  k_gemm<1><<<1024, 512, 0, stream>>>(xb, woT, out_b, nullptr, nullptr, nullptr,
                                      (float*)d_out, 2);
}

// Round 3
// 743.267 us; speedup vs baseline: 1.1691x; 1.1691x over previous
//
#include <hip/hip_runtime.h>
#include <hip/hip_bf16.h>
#include <stdint.h>

// Swin windowed MHA: N=32, H=W=64, C=512, heads=16, head_dim=32, window 8x8 (E=64).
// conv x->bf16 ; transpose weights ; GEMM1(qkv, 256^2 8-phase, LDS-transpose epilogue
// scattering to Q/K/VT with coalesced 16B stores) ; windowed attn ; GEMM2(out).

typedef __attribute__((ext_vector_type(4))) float  f32x4;
typedef __attribute__((ext_vector_type(4))) float  fvec4;
typedef __attribute__((ext_vector_type(8))) short  s16x8;
typedef __attribute__((ext_vector_type(8))) __bf16 bf16x8;
typedef __attribute__((ext_vector_type(2))) unsigned int u32x2;
typedef unsigned short u16;
typedef unsigned int   u32;
typedef __attribute__((ext_vector_type(4))) u16 u16x4;

__device__ __forceinline__ u16 f2bf(float f) {
  u32 u = __builtin_bit_cast(u32, f);
  u32 r = (u + 0x7FFFu + ((u >> 16) & 1u)) >> 16;
  return (u16)r;
}
__device__ __forceinline__ u32 pk2(float x, float y) {
  return (u32)f2bf(x) | ((u32)f2bf(y) << 16);
}

__device__ __forceinline__ f32x4 mfma16(s16x8 a, s16x8 b, f32x4 c) {
  return __builtin_amdgcn_mfma_f32_16x16x32_bf16((bf16x8)a, (bf16x8)b, c, 0, 0, 0);
}

__device__ __forceinline__ void gload16(const u16* g, u16* l) {
  __builtin_amdgcn_global_load_lds(
      (const __attribute__((address_space(1))) u32*)g,
      (__attribute__((address_space(3))) u32*)l, 16, 0, 0);
}

// ---------------- conversion kernels ----------------
__global__ void k_conv_x(const float* __restrict__ x, u16* __restrict__ xb, int n4) {
  int i = blockIdx.x * 256 + threadIdx.x;
  if (i >= n4) return;
  fvec4 v = ((const fvec4*)x)[i];
  u16x4 o;
  o.x = f2bf(v.x); o.y = f2bf(v.y); o.z = f2bf(v.z); o.w = f2bf(v.w);
  ((u16x4*)xb)[i] = o;
}

__global__ void k_transpose_w(const float* __restrict__ w, u16* __restrict__ wt, int K, int N) {
  int i = blockIdx.x * 256 + threadIdx.x;
  if (i >= K * N) return;
  int k = i / N, n = i - k * N;
  wt[n * K + k] = f2bf(w[i]);
}

// ---------------- GEMM: 256x256 tile, BK=64, 8 waves, 8-phase, K=512 fixed ----------------
// MODE 0: qkv projection; each N-tile (256 cols) is entirely inside Q, K, or V section.
//   Epilogue: acc -> LDS (4x4 lane transpose for Q/K [m][n]; direct b64 for V [n][m]),
//   then coalesced 16B stores into the attn-friendly layouts.
// MODE 1: out projection -> fp32 Out, two 128-row passes through LDS, 16B stores.
template <int MODE>
__global__ __launch_bounds__(512, 2)
void k_gemm(const u16* __restrict__ A, const u16* __restrict__ B,
            const float* __restrict__ bias,
            u16* __restrict__ Qb, u16* __restrict__ Kb, u16* __restrict__ VT,
            float* __restrict__ Out, int ntn) {
  __shared__ u16 lds[65536];           // 128 KiB: K-loop dbuf, then C-tile
  u16* ldsA = lds;                      // [2][16384]
  u16* ldsB = lds + 32768;              // [2][16384]
  const int tid = threadIdx.x;
  const int lane = tid & 63, wid = tid >> 6;
  const int quad = lane >> 4, col_l = lane & 15;
  const int wr = wid >> 2, wc = wid & 3;  // 2 x 4 wave grid; wave tile 128 x 64

  // XCD-chunked bijective swizzle (gridDim.x % 8 == 0)
  const int cpx = gridDim.x >> 3;
  const int sb = (blockIdx.x & 7) * cpx + (blockIdx.x >> 3);
  const int mt = sb / ntn, nt = sb - mt * ntn;
  const int m0 = mt * 256, n0 = nt * 256;

  const int srow = tid >> 3;
  const int sch = (tid & 7) ^ (srow & 7);
  const size_t gA = (size_t)(m0 + srow) * 512 + sch * 8;
  const size_t gB = (size_t)(n0 + srow) * 512 + sch * 8;

  auto STAGE = [&](int s) {
    const int b = s & 1;
    const size_t k = (size_t)s * 64;
#pragma unroll
    for (int g = 0; g < 4; ++g) {
      gload16(A + gA + (size_t)g * 32768 + k, &ldsA[b * 16384 + g * 4096 + tid * 8]);
      gload16(B + gB + (size_t)g * 32768 + k, &ldsB[b * 16384 + g * 4096 + tid * 8]);
    }
  };

  STAGE(0);
  STAGE(1);
  asm volatile("s_waitcnt vmcnt(8)" ::: "memory");
  asm volatile("s_barrier" ::: "memory");

  const int xsw = (col_l & 7) << 3;
  const int aRB = (wr * 128 + col_l) * 64;
  const int bRB = (wc * 64 + col_l) * 64;

  f32x4 acc[8][4] = {};

  for (int t = 0; t < 8; ++t) {
    const int bu = t & 1;
    s16x8 af[4][2], bf[4][2];

#pragma unroll
    for (int r = 0; r < 4; ++r)
#pragma unroll
      for (int kk = 0; kk < 2; ++kk)
        af[r][kk] = *(const s16x8*)&ldsA[bu * 16384 + aRB + r * 1024 + ((kk * 32 + quad * 8) ^ xsw)];
#pragma unroll
    for (int c = 0; c < 4; ++c)
      bf[c][0] = *(const s16x8*)&ldsB[bu * 16384 + bRB + c * 1024 + ((quad * 8) ^ xsw)];
    asm volatile("s_barrier" ::: "memory");
    __builtin_amdgcn_s_setprio(1);
#pragma unroll
    for (int r = 0; r < 4; ++r)
#pragma unroll
      for (int c = 0; c < 4; ++c)
        acc[r][c] = mfma16(af[r][0], bf[c][0], acc[r][c]);
    __builtin_amdgcn_s_setprio(0);
    asm volatile("s_barrier" ::: "memory");

#pragma unroll
    for (int c = 0; c < 4; ++c)
      bf[c][1] = *(const s16x8*)&ldsB[bu * 16384 + bRB + c * 1024 + ((32 + quad * 8) ^ xsw)];
    asm volatile("s_barrier" ::: "memory");
    __builtin_amdgcn_s_setprio(1);
#pragma unroll
    for (int r = 0; r < 4; ++r)
#pragma unroll
      for (int c = 0; c < 4; ++c)
        acc[r][c] = mfma16(af[r][1], bf[c][1], acc[r][c]);
    __builtin_amdgcn_s_setprio(0);
    asm volatile("s_barrier" ::: "memory");

#pragma unroll
    for (int r = 0; r < 4; ++r)
#pragma unroll
      for (int kk = 0; kk < 2; ++kk)
        af[r][kk] = *(const s16x8*)&ldsA[bu * 16384 + aRB + (r + 4) * 1024 + ((kk * 32 + quad * 8) ^ xsw)];
    asm volatile("s_barrier" ::: "memory");
    __builtin_amdgcn_s_setprio(1);
#pragma unroll
    for (int r = 0; r < 4; ++r)
#pragma unroll
      for (int c = 0; c < 4; ++c)
        acc[r + 4][c] = mfma16(af[r][0], bf[c][0], acc[r + 4][c]);
    __builtin_amdgcn_s_setprio(0);
    asm volatile("s_barrier" ::: "memory");

    if (t < 6) STAGE(t + 2);
    asm volatile("s_barrier" ::: "memory");
    __builtin_amdgcn_s_setprio(1);
#pragma unroll
    for (int r = 0; r < 4; ++r)
#pragma unroll
      for (int c = 0; c < 4; ++c)
        acc[r + 4][c] = mfma16(af[r][1], bf[c][1], acc[r + 4][c]);
    __builtin_amdgcn_s_setprio(0);
    if (t < 6)
      asm volatile("s_waitcnt vmcnt(8)" ::: "memory");
    else if (t == 6)
      asm volatile("s_waitcnt vmcnt(0)" ::: "memory");
    asm volatile("s_barrier" ::: "memory");
  }

  // ---- epilogue via LDS transpose (the K-loop dbuf is dead now) ----
  const int hb = (m0 >> 6) & 63;      // h base (multiple of 4)
  const int nimg = m0 >> 12;
  const int headbase = (n0 >> 5) & 15;

  if (MODE == 0) {
    const int which = n0 >> 9;        // 0=Q, 1=K, 2=V
    if (which < 2) {
      // ---- [m][n] u16, chunk swizzle ^(m&7); 4x4 lane transpose -> b64 writes
      float bv[4];
#pragma unroll
      for (int c = 0; c < 4; ++c) bv[c] = bias[n0 + wc * 64 + c * 16 + col_l];
#pragma unroll
      for (int r = 0; r < 8; ++r) {
#pragma unroll
        for (int c = 0; c < 4; ++c) {
          float v0 = acc[r][c][0] + bv[c], v1 = acc[r][c][1] + bv[c];
          float v2 = acc[r][c][2] + bv[c], v3 = acc[r][c][3] + bv[c];
          float sA = (lane & 1) ? v0 : v1; sA = __shfl_xor(sA, 1);
          float sB = (lane & 1) ? v2 : v3; sB = __shfl_xor(sB, 1);
          u32 a, b;
          if (lane & 1) { a = pk2(sA, v1); b = pk2(sB, v3); }
          else          { a = pk2(v0, sA); b = pk2(v2, sB); }
          u32 s2 = (lane & 2) ? a : b;
          s2 = (u32)__shfl_xor((int)s2, 2);
          u32x2 val;
          if (lane & 2) { val.x = s2; val.y = b; }
          else          { val.x = a;  val.y = s2; }
          const int m = wr * 128 + r * 16 + quad * 4 + (col_l & 3);
          const int nc = wc * 64 + c * 16 + (col_l & ~3);
          const int nck = nc >> 3, half = (nc >> 2) & 1;
          *(u32x2*)((char*)lds + m * 512 + (((nck ^ (m & 7)) << 4) + half * 8)) = val;
        }
      }
      __syncthreads();
      u16* dst = (which == 0) ? Qb : Kb;
      const int head = headbase + wid;
#pragma unroll
      for (int it = 0; it < 16; ++it) {
        const int b = it & 7, hrhi = it >> 3;
        const int hrow = hrhi * 2 + (lane >> 5);
        const int elow = (lane >> 2) & 7, dch = lane & 3;
        const int m_loc = hrow * 64 + b * 8 + elow;
        const int nck = wid * 4 + dch;
        s16x8 val = *(const s16x8*)((char*)lds + m_loc * 512 + ((nck ^ (m_loc & 7)) << 4));
        const int h = hb + hrow;
        const int win = nimg * 64 + (h >> 3) * 8 + b;
        const int e = (h & 7) * 8 + elow;
        *(s16x8*)&dst[((size_t)(win * 16 + head) * 64 + e) * 32 + dch * 8] = val;
      }
    } else {
      // ---- V: [n][m] u16 (transposed), direct b64 writes, swizzle ^(n&7)
#pragma unroll
      for (int c = 0; c < 4; ++c) {
        const float bv = bias[n0 + wc * 64 + c * 16 + col_l];
        const int n = wc * 64 + c * 16 + col_l;
#pragma unroll
        for (int r = 0; r < 8; ++r) {
          u32x2 val;
          val.x = pk2(acc[r][c][0] + bv, acc[r][c][1] + bv);
          val.y = pk2(acc[r][c][2] + bv, acc[r][c][3] + bv);
          const int mloc = wr * 128 + r * 16 + quad * 4;
          const int mck = mloc >> 3, half = (mloc >> 2) & 1;
          *(u32x2*)((char*)lds + n * 512 + ((mck ^ (n & 7)) << 4) + half * 8) = val;
        }
      }
      __syncthreads();
      const int head = headbase + wid;
#pragma unroll
      for (int it = 0; it < 16; ++it) {
        const int b = it & 7, dhi = it >> 3;
        const int d = dhi * 16 + ((lane >> 2) & 15);
        const int hrow = lane & 3;
        const int nloc = wid * 32 + d;
        const int mck = hrow * 8 + b;
        s16x8 val = *(const s16x8*)((char*)lds + nloc * 512 + ((mck ^ (nloc & 7)) << 4));
        const int h = hb + hrow;
        const int win = nimg * 64 + (h >> 3) * 8 + b;
        const int e0 = (h & 7) * 8;
        *(s16x8*)&VT[((size_t)(win * 16 + head) * 32 + d) * 64 + e0] = val;
      }
    }
  } else {
    // ---- MODE 1: fp32 out, two 128-row passes through LDS (f32 [128][256])
#pragma unroll
    for (int p = 0; p < 2; ++p) {
      if (p) __syncthreads();
#pragma unroll
      for (int c = 0; c < 4; ++c) {
        const float bv = bias[n0 + wc * 64 + c * 16 + col_l];
#pragma unroll
        for (int rr = 0; rr < 4; ++rr) {
          const int r = p * 4 + rr;
          float v0 = acc[r][c][0] + bv, v1 = acc[r][c][1] + bv;
          float v2 = acc[r][c][2] + bv, v3 = acc[r][c][3] + bv;
          float sA = (lane & 1) ? v0 : v1; sA = __shfl_xor(sA, 1);
          float sB = (lane & 1) ? v2 : v3; sB = __shfl_xor(sB, 1);
          float A0, A1, B0, B1;
          if (lane & 1) { A0 = sA; A1 = v1; B0 = sB; B1 = v3; }
          else          { A0 = v0; A1 = sA; B0 = v2; B1 = sB; }
          float t0 = (lane & 2) ? A0 : B0; t0 = __shfl_xor(t0, 2);
          float t1 = (lane & 2) ? A1 : B1; t1 = __shfl_xor(t1, 2);
          f32x4 outv;
          if (lane & 2) { outv[0] = t0; outv[1] = t1; outv[2] = B0; outv[3] = B1; }
          else          { outv[0] = A0; outv[1] = A1; outv[2] = t0; outv[3] = t1; }
          const int lr = wr * 64 + rr * 16 + quad * 4 + (col_l & 3);
          const int ck = (wc * 64 + c * 16 + (col_l & ~3)) >> 2;
          *(f32x4*)((char*)lds + lr * 1024 + ((ck ^ (lr & 7)) << 4)) = outv;
        }
      }
      __syncthreads();
#pragma unroll
      for (int it = 0; it < 16; ++it) {
        const int lr = wid * 16 + it;
        f32x4 v = *(const f32x4*)((char*)lds + lr * 1024 + (((int)lane ^ (lr & 7)) << 4));
        const int m = m0 + (lr >> 6) * 128 + p * 64 + (lr & 63);
        *(f32x4*)&Out[(size_t)m * 512 + n0 + lane * 4] = v;
      }
    }
  }
}

// ---------------- windowed attention (unchanged) ----------------
__global__ __launch_bounds__(256, 2)
void k_attn(const u16* __restrict__ Q, const u16* __restrict__ K,
            const u16* __restrict__ VT, const float* __restrict__ mask,
            const float* __restrict__ btab, u16* __restrict__ AO) {
  __shared__ u16 plds[4 * 4096];
  const int tid = threadIdx.x;
  const int wid = tid >> 6, lane = tid & 63;
  const int quad = lane >> 4, col_l = lane & 15;
  const int bid = blockIdx.x;
  const int win = bid >> 2;
  const int head = ((bid & 3) << 2) | wid;
  const int nimg = win >> 6, a = (win >> 3) & 7, b = win & 7;
  const size_t wh = (size_t)(win * 16 + head);
  const u16* qb  = Q  + wh * 2048;
  const u16* kb  = K  + wh * 2048;
  const u16* vtb = VT + wh * 2048;

  s16x8 aq[4], bk[4];
#pragma unroll
  for (int t = 0; t < 4; ++t) {
    aq[t] = *(const s16x8*)&qb[(t * 16 + col_l) * 32 + quad * 8];
    bk[t] = *(const s16x8*)&kb[(t * 16 + col_l) * 32 + quad * 8];
  }
  f32x4 s[4][4] = {};
#pragma unroll
  for (int r = 0; r < 4; ++r)
#pragma unroll
    for (int c = 0; c < 4; ++c)
      s[r][c] = mfma16(aq[r], bk[c], s[r][c]);

  const float scale = 0.17677669529663687f;  // 1/sqrt(32)
  const float* mrow = mask + (size_t)(a * 8 + b) * 4096;
#pragma unroll
  for (int r = 0; r < 4; ++r)
#pragma unroll
    for (int c = 0; c < 4; ++c)
#pragma unroll
      for (int i = 0; i < 4; ++i) {
        const int row = r * 16 + quad * 4 + i, col = c * 16 + col_l;
        const int dh = (row >> 3) - (col >> 3) + 7;
        const int dw = (row & 7) - (col & 7) + 7;
        s[r][c][i] = s[r][c][i] * scale + btab[(dh * 15 + dw) * 16 + head] +
                     mrow[row * 64 + col];
      }

  float rinv[4][4];
#pragma unroll
  for (int r = 0; r < 4; ++r) {
#pragma unroll
    for (int i = 0; i < 4; ++i) {
      float mx = fmaxf(fmaxf(s[r][0][i], s[r][1][i]), fmaxf(s[r][2][i], s[r][3][i]));
      mx = fmaxf(mx, __shfl_xor(mx, 1));
      mx = fmaxf(mx, __shfl_xor(mx, 2));
      mx = fmaxf(mx, __shfl_xor(mx, 4));
      mx = fmaxf(mx, __shfl_xor(mx, 8));
      float sum = 0.f;
#pragma unroll
      for (int c = 0; c < 4; ++c) {
        float p = __expf(s[r][c][i] - mx);
        s[r][c][i] = p;
        sum += p;
      }
      sum += __shfl_xor(sum, 1);
      sum += __shfl_xor(sum, 2);
      sum += __shfl_xor(sum, 4);
      sum += __shfl_xor(sum, 8);
      rinv[r][i] = 1.0f / sum;
    }
  }

  u16* pl = &plds[wid * 4096];
#pragma unroll
  for (int r = 0; r < 4; ++r)
#pragma unroll
    for (int c = 0; c < 4; ++c)
#pragma unroll
      for (int i = 0; i < 4; ++i) {
        const int row = r * 16 + quad * 4 + i, col = c * 16 + col_l;
        const int off = (row * 128 + col * 2) ^ ((row & 7) << 4);
        *(u16*)((char*)pl + off) = f2bf(s[r][c][i]);
      }
  __syncthreads();

  s16x8 bv[2][2];
#pragma unroll
  for (int c2 = 0; c2 < 2; ++c2)
#pragma unroll
    for (int ks = 0; ks < 2; ++ks)
      bv[c2][ks] = *(const s16x8*)&vtb[(c2 * 16 + col_l) * 64 + ks * 32 + quad * 8];

  f32x4 o[4][2] = {};
#pragma unroll
  for (int r = 0; r < 4; ++r) {
#pragma unroll
    for (int ks = 0; ks < 2; ++ks) {
      const int row = r * 16 + col_l;
      const int off = (row * 128 + (ks * 32 + quad * 8) * 2) ^ ((row & 7) << 4);
      s16x8 pa = *(const s16x8*)((char*)pl + off);
#pragma unroll
      for (int c2 = 0; c2 < 2; ++c2)
        o[r][c2] = mfma16(pa, bv[c2][ks], o[r][c2]);
    }
  }

#pragma unroll
  for (int r = 0; r < 4; ++r) {
#pragma unroll
    for (int i = 0; i < 4; ++i) {
      const int row = r * 16 + quad * 4 + i;
      const int h = a * 8 + (row >> 3), w = b * 8 + (row & 7);
      const size_t m = (size_t)nimg * 4096 + (size_t)h * 64 + w;
      const float inv = rinv[r][i];
#pragma unroll
      for (int c2 = 0; c2 < 2; ++c2)
        AO[m * 512 + head * 32 + c2 * 16 + col_l] = f2bf(o[r][c2][i] * inv);
    }
  }
}

// ---------------- launch ----------------
extern "C" void kernel_launch(void* const* d_in, const int* in_sizes, int n_in,
                              void* d_out, int out_size, void* d_ws, size_t ws_size,
                              hipStream_t stream) {
  const float* x     = (const float*)d_in[0];
  const float* mask  = (const float*)d_in[1];
  const float* qkv_w = (const float*)d_in[2];
  const float* qkv_b = (const float*)d_in[3];
  const float* out_w = (const float*)d_in[4];
  const float* out_b = (const float*)d_in[5];
  const float* btab  = (const float*)d_in[6];

  char* ws = (char*)d_ws;
  u16* xb    = (u16*)ws;                        // 134,217,728 B (x bf16, reused as attn_out)
  u16* vt    = (u16*)(ws + 134217728);          // 134,217,728 B (V^T)
  u16* wqkvT = (u16*)(ws + 268435456);          // 1,572,864 B
  u16* woT   = (u16*)(ws + 270008320);          // 524,288 B

  u16* Qb = (u16*)d_out;                        // 134,217,728 B
  u16* Kb = (u16*)d_out + 67108864;             // 134,217,728 B

  k_conv_x<<<65536, 256, 0, stream>>>(x, xb, 16777216);
  k_transpose_w<<<3072, 256, 0, stream>>>(qkv_w, wqkvT, 512, 1536);
  k_transpose_w<<<1024, 256, 0, stream>>>(out_w, woT, 512, 512);
  k_gemm<0><<<3072, 512, 0, stream>>>(xb, wqkvT, qkv_b, Qb, Kb, vt, nullptr, 6);
  k_attn<<<8192, 256, 0, stream>>>(Qb, Kb, vt, mask, btab, xb);
  k_gemm<1><<<1024, 512, 0, stream>>>(xb, woT, out_b, nullptr, nullptr, nullptr,
                                      (float*)d_out, 2);
}